// Round 2
// baseline (142.864 us; speedup 1.0000x reference)
//
#include <hip/hip_runtime.h>
#include <math.h>

#define IMG 256
#define MAX_R 64

// d_ws layout: [0]=count (unsigned), offset 16: int4 params[4095]
//   params.x = px_int, params.y = pr*pr, params.z = depth bits, params.w = unused

// ---------------------------------------------------------------------------
// Kernel A: single block, 1024 threads. Computes per-entity camera params
// (identical f32/f64 op sequence to the validated round-1 kernel) and
// compacts valid entities into d_ws via an LDS counter.
// ---------------------------------------------------------------------------
__global__ __launch_bounds__(1024) void compact_kernel(
    const float* __restrict__ agent_pos,
    const float* __restrict__ goal_pos,
    const float* __restrict__ other_agents,
    const float* __restrict__ obstacles,
    unsigned int* __restrict__ count_out,
    int4* __restrict__ params,
    int n_ag, int n_ob)
{
    __shared__ unsigned int cnt;
    if (threadIdx.x == 0) cnt = 0;
    __syncthreads();

    // camera frame (uniform)
    const float ax = agent_pos[0], ay = agent_pos[1];
    const float gx = goal_pos[0], gy = goal_pos[1];
    const float vx = gx - ax, vy = gy - ay;
    const float nrm = sqrtf(vx * vx + vy * vy) + 1e-8f;
    const float s = vx / nrm;   // view[0]
    const float c = vy / nrm;   // view[1]

    const int n_total = n_ag + n_ob;
    for (int e = threadIdx.x; e < n_total; e += blockDim.x) {
        float ex, ey, radius, height;
        if (e < n_ag) {
            ex = other_agents[2 * e];
            ey = other_agents[2 * e + 1];
            radius = 0.05f;   // AGENT_RADIUS
            height = 0.2f;    // AGENT_HEIGHT
        } else {
            const int o = e - n_ag;
            ex = obstacles[3 * o];
            ey = obstacles[3 * o + 1];
            radius = obstacles[3 * o + 2];
            height = 0.5f;    // OBSTACLE_HEIGHT
        }

        const float rx = ex - ax, ry = ey - ay;
        const float cx = rx * c + ry * s;        // cam_x
        const float cy = ry * c - rx * s;        // cam_y
        const float dist = sqrtf(cx * cx + cy * cy);
        const float angle = (float)atan2((double)cx, (double)cy);

        const float half_fov = 0.78539816339744830962f; // f32(pi/4)
        const bool valid = (cy >= 0.0f) && (dist <= 3.0f) && (fabsf(angle) <= half_fov);
        if (!valid) continue;

        const float pixel_x = angle / half_fov * 0.5f;
        const int px_int = (int)floorf((pixel_x + 0.5f) * 256.0f);

        int pr = (int)floorf(radius / (dist + 1e-8f) * 256.0f * 0.5f);
        pr = min(max(pr, 1), MAX_R);

        float depth = fminf(dist / 3.0f, 1.0f) * (1.0f - height * 0.3f);
        depth = fmaxf(depth, 0.0f);

        const unsigned int idx = atomicAdd(&cnt, 1u);
        params[idx] = make_int4(px_int, pr * pr, __float_as_int(depth), 0);
    }

    __syncthreads();
    if (threadIdx.x == 0) *count_out = cnt;
}

// ---------------------------------------------------------------------------
// Kernel B: one block per image row, one thread per column. Gather-min over
// the compact entity list. Rows outside the reachable band [64,192] just
// write 1.0. Per-row scalar prune (dy^2 <= pr^2) is wave-uniform.
// Every pixel is written exactly once -> no init pass, no atomics.
// ---------------------------------------------------------------------------
__global__ __launch_bounds__(256) void raster_kernel(
    const unsigned int* __restrict__ count_in,
    const int4* __restrict__ params,
    float* __restrict__ img)
{
    const int row = blockIdx.x;
    const int px  = threadIdx.x;
    const int dy  = row - 128;          // IMG/2
    const int dy2 = dy * dy;

    float dmin = 1.0f;
    if (dy >= -MAX_R && dy <= MAX_R) {
        const int n = (int)(*count_in);   // uniform
        for (int i = 0; i < n; ++i) {
            const int4 p = params[i];     // uniform address -> scalar-cached
            if (dy2 <= p.y) {             // uniform branch: row-level prune
                const int dx = px - p.x;
                const int m  = dx * dx + dy2;
                if (m <= p.y) dmin = fminf(dmin, __int_as_float(p.z));
            }
        }
    }
    img[row * IMG + px] = dmin;
}

extern "C" void kernel_launch(void* const* d_in, const int* in_sizes, int n_in,
                              void* d_out, int out_size, void* d_ws, size_t ws_size,
                              hipStream_t stream) {
    const float* agent_pos    = (const float*)d_in[0];
    const float* goal_pos     = (const float*)d_in[1];
    const float* other_agents = (const float*)d_in[2];
    const float* obstacles    = (const float*)d_in[3];

    const int n_ag = in_sizes[2] / 2;   // 2047
    const int n_ob = in_sizes[3] / 3;   // 2048

    unsigned int* count = (unsigned int*)d_ws;
    int4* params = (int4*)((char*)d_ws + 16);

    compact_kernel<<<1, 1024, 0, stream>>>(
        agent_pos, goal_pos, other_agents, obstacles,
        count, params, n_ag, n_ob);

    raster_kernel<<<IMG, 256, 0, stream>>>(count, params, (float*)d_out);
}

// Round 3
// 82.698 us; speedup vs baseline: 1.7275x; 1.7275x over previous
//
#include <hip/hip_runtime.h>
#include <math.h>

#define IMG 256
#define MAX_R 64

// d_ws layout: [0] = unsigned count (zeroed via hipMemsetAsync node),
//              offset 16: int4 params[4095]  {px_int, pr*pr, depth_bits, 0}

// ---------------------------------------------------------------------------
// Kernel A: one thread per entity, 16 blocks x 256. Computes camera params
// (identical f32/f64 op sequence to the absmax-0.0-validated kernel) and
// compacts valid entities via wave-aggregated global atomicAdd.
// ---------------------------------------------------------------------------
__global__ __launch_bounds__(256) void param_kernel(
    const float* __restrict__ agent_pos,
    const float* __restrict__ goal_pos,
    const float* __restrict__ other_agents,
    const float* __restrict__ obstacles,
    unsigned int* __restrict__ count,
    int4* __restrict__ params,
    int n_ag, int n_ob)
{
    const int e = blockIdx.x * blockDim.x + threadIdx.x;
    const int n_total = n_ag + n_ob;
    if (e >= n_total) return;

    // camera frame (uniform)
    const float ax = agent_pos[0], ay = agent_pos[1];
    const float gx = goal_pos[0], gy = goal_pos[1];
    const float vx = gx - ax, vy = gy - ay;
    const float nrm = sqrtf(vx * vx + vy * vy) + 1e-8f;
    const float s = vx / nrm;   // view[0]
    const float c = vy / nrm;   // view[1]

    float ex, ey, radius, height;
    if (e < n_ag) {
        ex = other_agents[2 * e];
        ey = other_agents[2 * e + 1];
        radius = 0.05f;   // AGENT_RADIUS
        height = 0.2f;    // AGENT_HEIGHT
    } else {
        const int o = e - n_ag;
        ex = obstacles[3 * o];
        ey = obstacles[3 * o + 1];
        radius = obstacles[3 * o + 2];
        height = 0.5f;    // OBSTACLE_HEIGHT
    }

    const float rx = ex - ax, ry = ey - ay;
    const float cx = rx * c + ry * s;        // cam_x
    const float cy = ry * c - rx * s;        // cam_y
    const float dist = sqrtf(cx * cx + cy * cy);
    const float angle = (float)atan2((double)cx, (double)cy);

    const float half_fov = 0.78539816339744830962f; // f32(pi/4)
    const bool valid = (cy >= 0.0f) && (dist <= 3.0f) && (fabsf(angle) <= half_fov);
    if (!valid) return;

    const float pixel_x = angle / half_fov * 0.5f;
    const int px_int = (int)floorf((pixel_x + 0.5f) * 256.0f);

    int pr = (int)floorf(radius / (dist + 1e-8f) * 256.0f * 0.5f);
    pr = min(max(pr, 1), MAX_R);

    float depth = fminf(dist / 3.0f, 1.0f) * (1.0f - height * 0.3f);
    depth = fmaxf(depth, 0.0f);

    const unsigned int idx = atomicAdd(count, 1u);   // wave-aggregated
    params[idx] = make_int4(px_int, pr * pr, __float_as_int(depth), 0);
}

// ---------------------------------------------------------------------------
// Kernel B: one block per row, 1024 threads = 4 groups x 256 columns.
// Entities staged into LDS tiles (coalesced), inner loop is an LDS
// broadcast read (conflict-free) + ~5 VALU ops. Entity list split across
// the 4 groups, LDS min-reduce at the end. No atomics, no init pass.
// ---------------------------------------------------------------------------
__global__ __launch_bounds__(1024) void raster_kernel(
    const unsigned int* __restrict__ count_in,
    const int4* __restrict__ params,
    float* __restrict__ img)
{
    __shared__ int4 tile[1024];
    __shared__ float pmin[4][256];

    const int row = blockIdx.x;
    const int tid = threadIdx.x;
    const int col = tid & 255;
    const int grp = tid >> 8;          // wave-uniform (4 waves per group)
    const int dy  = row - 128;         // IMG/2
    const int dy2 = dy * dy;

    if (dy < -MAX_R || dy > MAX_R) {   // unreachable rows: plain 1.0
        if (tid < 256) img[row * IMG + tid] = 1.0f;
        return;
    }

    const int n = (int)(*count_in);
    float dmin = 1.0f;
    for (int base = 0; base < n; base += 1024) {
        const int m = min(1024, n - base);
        __syncthreads();
        if (tid < m) tile[tid] = params[base + tid];   // coalesced int4
        __syncthreads();
        for (int i = grp; i < m; i += 4) {             // LDS broadcast reads
            const int4 p = tile[i];
            const int dx = col - p.x;
            if (dx * dx + dy2 <= p.y) dmin = fminf(dmin, __int_as_float(p.z));
        }
    }
    pmin[grp][col] = dmin;
    __syncthreads();
    if (grp == 0) {
        const float d = fminf(fminf(pmin[0][col], pmin[1][col]),
                              fminf(pmin[2][col], pmin[3][col]));
        img[row * IMG + col] = d;
    }
}

extern "C" void kernel_launch(void* const* d_in, const int* in_sizes, int n_in,
                              void* d_out, int out_size, void* d_ws, size_t ws_size,
                              hipStream_t stream) {
    const float* agent_pos    = (const float*)d_in[0];
    const float* goal_pos     = (const float*)d_in[1];
    const float* other_agents = (const float*)d_in[2];
    const float* obstacles    = (const float*)d_in[3];

    const int n_ag = in_sizes[2] / 2;   // 2047
    const int n_ob = in_sizes[3] / 3;   // 2048
    const int n_total = n_ag + n_ob;

    unsigned int* count = (unsigned int*)d_ws;
    int4* params = (int4*)((char*)d_ws + 16);

    hipMemsetAsync(d_ws, 0, 4, stream);   // zero the compaction counter

    param_kernel<<<(n_total + 255) / 256, 256, 0, stream>>>(
        agent_pos, goal_pos, other_agents, obstacles,
        count, params, n_ag, n_ob);

    raster_kernel<<<IMG, 1024, 0, stream>>>(count, params, (float*)d_out);
}

// Round 5
// 78.092 us; speedup vs baseline: 1.8294x; 1.0590x over previous
//
#include <hip/hip_runtime.h>
#include <math.h>

#define IMG 256
#define MAX_R 64

// d_ws layout: int2 params[4095] at offset 0.
//   params.x = (px_int << 13) | pr*pr   (0 when invalid)
//   params.y = depth bits               (1.0f when invalid -> harmless)

// ---------------------------------------------------------------------------
// Kernel A: 64 blocks x 256 threads.
//   - every thread writes one float4 of the 1.0-initialized image
//   - threads with gid < n_total compute entity params (validated f32/f64
//     op sequence) and store them at FIXED index (no compaction/atomics).
// ---------------------------------------------------------------------------
__global__ __launch_bounds__(256) void param_init_kernel(
    const float* __restrict__ agent_pos,
    const float* __restrict__ goal_pos,
    const float* __restrict__ other_agents,
    const float* __restrict__ obstacles,
    int2* __restrict__ params,
    float4* __restrict__ img4,
    int n_ag, int n_ob)
{
    const int gid = blockIdx.x * blockDim.x + threadIdx.x;

    // image init: 64*256 = 16384 float4 = 65536 floats
    img4[gid] = make_float4(1.0f, 1.0f, 1.0f, 1.0f);

    const int n_total = n_ag + n_ob;
    if (gid >= n_total) return;
    const int e = gid;

    // camera frame (uniform)
    const float ax = agent_pos[0], ay = agent_pos[1];
    const float gx = goal_pos[0], gy = goal_pos[1];
    const float vx = gx - ax, vy = gy - ay;
    const float nrm = sqrtf(vx * vx + vy * vy) + 1e-8f;
    const float s = vx / nrm;   // view[0]
    const float c = vy / nrm;   // view[1]

    float ex, ey, radius, height;
    if (e < n_ag) {
        ex = other_agents[2 * e];
        ey = other_agents[2 * e + 1];
        radius = 0.05f;   // AGENT_RADIUS
        height = 0.2f;    // AGENT_HEIGHT
    } else {
        const int o = e - n_ag;
        ex = obstacles[3 * o];
        ey = obstacles[3 * o + 1];
        radius = obstacles[3 * o + 2];
        height = 0.5f;    // OBSTACLE_HEIGHT
    }

    const float rx = ex - ax, ry = ey - ay;
    const float cx = rx * c + ry * s;        // cam_x
    const float cy = ry * c - rx * s;        // cam_y
    const float dist = sqrtf(cx * cx + cy * cy);
    const float angle = (float)atan2((double)cx, (double)cy);

    const float half_fov = 0.78539816339744830962f; // f32(pi/4)
    const bool valid = (cy >= 0.0f) && (dist <= 3.0f) && (fabsf(angle) <= half_fov);

    int2 out;
    if (valid) {
        const float pixel_x = angle / half_fov * 0.5f;
        const int px_int = (int)floorf((pixel_x + 0.5f) * 256.0f);  // [0,256]

        int pr = (int)floorf(radius / (dist + 1e-8f) * 256.0f * 0.5f);
        pr = min(max(pr, 1), MAX_R);

        float depth = fminf(dist / 3.0f, 1.0f) * (1.0f - height * 0.3f);
        depth = fmaxf(depth, 0.0f);

        out.x = (px_int << 13) | (pr * pr);   // pr*pr <= 4096 < 8192
        out.y = __float_as_int(depth);
    } else {
        out.x = 0;                  // pr2 = 0, px = 0
        out.y = __float_as_int(1.0f);  // renders as no-op
    }
    params[e] = out;
}

// ---------------------------------------------------------------------------
// Kernel B: grid (129 rows, 4 entity-chunks) x 256 threads (1 col/thread).
// Filter-compact this chunk's entities by dy^2 <= pr^2 into LDS, then the
// per-column min loop reads int2 via uniform LDS broadcast. Partial results
// combine across chunks with atomicMin (f32>=0 -> uint min), skipped when
// the block contributes nothing.
// ---------------------------------------------------------------------------
#define CHUNK 1024

__global__ __launch_bounds__(256) void raster_kernel(
    const int2* __restrict__ params,
    unsigned int* __restrict__ img,
    int n_total)
{
    __shared__ int2 surv[CHUNK];
    __shared__ unsigned int cnt;

    const int row = 64 + blockIdx.x;        // band rows 64..192
    const int col = threadIdx.x;
    const int dy  = row - 128;
    const int dy2 = dy * dy;

    if (threadIdx.x == 0) cnt = 0;
    __syncthreads();

    // filter: 4 coalesced int2 loads per thread
    const int base = blockIdx.y * CHUNK;
    const int lim  = min(CHUNK, n_total - base);
    for (int k = threadIdx.x; k < lim; k += 256) {
        const int2 p = params[base + k];
        if (p.x != 0 && dy2 <= (p.x & 8191)) {
            const unsigned int idx = atomicAdd(&cnt, 1u);
            surv[idx] = p;
        }
    }
    __syncthreads();

    const int m = (int)cnt;
    float dmin = 1.0f;
    #pragma unroll 4
    for (int i = 0; i < m; ++i) {
        const int2 p = surv[i];             // uniform LDS broadcast (b64)
        const int dx = col - (p.x >> 13);
        if (dx * dx + dy2 <= (p.x & 8191)) dmin = fminf(dmin, __int_as_float(p.y));
    }

    if (dmin < 1.0f) {
        atomicMin(&img[row * IMG + col], __float_as_uint(dmin));
    }
}

extern "C" void kernel_launch(void* const* d_in, const int* in_sizes, int n_in,
                              void* d_out, int out_size, void* d_ws, size_t ws_size,
                              hipStream_t stream) {
    const float* agent_pos    = (const float*)d_in[0];
    const float* goal_pos     = (const float*)d_in[1];
    const float* other_agents = (const float*)d_in[2];
    const float* obstacles    = (const float*)d_in[3];

    const int n_ag = in_sizes[2] / 2;   // 2047
    const int n_ob = in_sizes[3] / 3;   // 2048
    const int n_total = n_ag + n_ob;    // 4095

    int2* params = (int2*)d_ws;

    param_init_kernel<<<64, 256, 0, stream>>>(
        agent_pos, goal_pos, other_agents, obstacles,
        params, (float4*)d_out, n_ag, n_ob);

    const int n_chunks = (n_total + CHUNK - 1) / CHUNK;   // 4
    raster_kernel<<<dim3(129, n_chunks), 256, 0, stream>>>(
        params, (unsigned int*)d_out, n_total);
}